// Round 14
// baseline (26.455 us; speedup 1.0000x reference)
//
#include <hip/hip_runtime.h>
#include <math.h>

#define B_TOTAL 16384
#define NQ 512
#define NUM 3

// One wave per batch, 4 waves/block, no LDS, minimal traffic:
// read ALL conf (coalesced, 32 MB total) but only the ~5 pos rows the greedy
// scan actually visits (wave-uniform 1-line broadcast loads). Iterative
// greedy: DPP-argmax (pure VALU, ~100cy chain; R13-validated exact stable
// tie-break) -> consume -> load row -> guard-band angle test -> accept until
// 3 found. All control flow is wave-uniform. Accepted-set zero-vector
// auto-pass mirrors the reference's masked-inf semantics.
typedef unsigned u32;

__device__ __forceinline__ u32 wave_umax_dpp(u32 v) {
    u32 r = v, t;
    t = (u32)__builtin_amdgcn_update_dpp(0, (int)r, 0x111, 0xF, 0xF, false);
    r = t > r ? t : r;   // row_shr:1
    t = (u32)__builtin_amdgcn_update_dpp(0, (int)r, 0x112, 0xF, 0xF, false);
    r = t > r ? t : r;   // row_shr:2
    t = (u32)__builtin_amdgcn_update_dpp(0, (int)r, 0x114, 0xF, 0xF, false);
    r = t > r ? t : r;   // row_shr:4
    t = (u32)__builtin_amdgcn_update_dpp(0, (int)r, 0x118, 0xF, 0xF, false);
    r = t > r ? t : r;   // row_shr:8
    t = (u32)__builtin_amdgcn_update_dpp(0, (int)r, 0x142, 0xF, 0xF, false);
    r = t > r ? t : r;   // row_bcast:15
    t = (u32)__builtin_amdgcn_update_dpp(0, (int)r, 0x143, 0xF, 0xF, false);
    r = t > r ? t : r;   // row_bcast:31
    return (u32)__builtin_amdgcn_readlane((int)r, 63);  // wave-uniform
}

__device__ __forceinline__ u32 wave_umin_dpp(u32 v) {
    u32 r = v, t;
    t = (u32)__builtin_amdgcn_update_dpp(-1, (int)r, 0x111, 0xF, 0xF, false);
    r = t < r ? t : r;
    t = (u32)__builtin_amdgcn_update_dpp(-1, (int)r, 0x112, 0xF, 0xF, false);
    r = t < r ? t : r;
    t = (u32)__builtin_amdgcn_update_dpp(-1, (int)r, 0x114, 0xF, 0xF, false);
    r = t < r ? t : r;
    t = (u32)__builtin_amdgcn_update_dpp(-1, (int)r, 0x118, 0xF, 0xF, false);
    r = t < r ? t : r;
    t = (u32)__builtin_amdgcn_update_dpp(-1, (int)r, 0x142, 0xF, 0xF, false);
    r = t < r ? t : r;
    t = (u32)__builtin_amdgcn_update_dpp(-1, (int)r, 0x143, 0xF, 0xF, false);
    r = t < r ? t : r;
    return (u32)__builtin_amdgcn_readlane((int)r, 63);  // wave-uniform
}

__global__ __launch_bounds__(256) void greedy_nms_kernel(
    const float* __restrict__ conf,   // [B, NQ]
    const float* __restrict__ pos,    // [B, NQ, 3]
    float* __restrict__ out)          // [B, NUM, 3]
{
    const int lane = threadIdx.x & 63;
    const int b = (blockIdx.x << 2) | (threadIdx.x >> 6);   // grid*4 == B

    const float* cb = conf + (size_t)b * NQ;
    const float* pb = pos  + (size_t)b * NQ * 3;

    // conf: lane owns elements 8l..8l+7 (two 1KB-coalesced float4 loads)
    const float4* cb4 = reinterpret_cast<const float4*>(cb);
    const float4 c0 = cb4[lane * 2 + 0];
    const float4 c1 = cb4[lane * 2 + 1];
    // fallback row 0 (single broadcast line)
    const float p0x = pb[0], p0y = pb[1], p0z = pb[2];

    // monotone float->u32 keys; key 0 == consumed (no NaN/-inf in input)
    u32 k[8];
    {
        float f[8] = {c0.x, c0.y, c0.z, c0.w, c1.x, c1.y, c1.z, c1.w};
        #pragma unroll
        for (int s = 0; s < 8; ++s) {
            int bi = __float_as_int(f[s]);
            k[s] = (u32)bi ^ ((u32)(bi >> 31) | 0x80000000u);
        }
    }

    // exact argmax via two DPP reduces (R13-validated):
    // returns wave-uniform element index; gm_out==0 => keys exhausted.
    // n = 8*lane + s; first equal slot (ascending s) + umin over n give the
    // reference's stable smaller-index tie-break exactly.
    auto argmax_dpp = [&](u32& gm_out) -> int {
        u32 m = k[0];
        #pragma unroll
        for (int s = 1; s < 8; ++s) m = k[s] > m ? k[s] : m;
        const u32 gm = wave_umax_dpp(m);
        int im = 8;
        #pragma unroll
        for (int s = 7; s >= 0; --s)
            if (k[s] == gm) im = s;                 // first equal slot
        const u32 candn = (im < 8) ? (u32)((lane << 3) | im) : 0xFFFFFFFFu;
        const u32 n = wave_umin_dpp(candn);
        gm_out = gm;
        return (int)n;
    };

    auto consume = [&](int n) {
        const int ci = ((n >> 3) == lane) ? (n & 7) : 8;
        #pragma unroll
        for (int s = 0; s < 8; ++s)
            if (ci == s) k[s] = 0u;
    };

    const float TH  = 0.78539816339744830961f; // pi/4 (f32 == jnp thresh)
    const float CLO = 0.70710478f;             // cos(pi/4) - ~2e-6
    const float CHI = 0.70710878f;             // cos(pi/4) + ~2e-6

    auto passv = [&](float ax, float ay, float az,
                     float px, float py, float pz) -> bool {
        float d = fabsf(ax * px + ay * py + az * pz);
        if (d <= CLO) return true;                  // clearly >= pi/4
        if (d >= CHI) return false;                 // clearly <  pi/4
        return acosf(fminf(d, 1.f)) >= TH;          // exact at boundary
    };

    // ---- #1: global argmax (always exists) ----
    u32 gm1;
    const int w1 = argmax_dpp(gm1);
    consume(w1);
    const float p1x = pb[w1 * 3 + 0];               // broadcast 1-line load
    const float p1y = pb[w1 * 3 + 1];
    const float p1z = pb[w1 * 3 + 2];

    // accepted-set state (a1 zero vector auto-passes until #2 found)
    float a1x = 0.f, a1y = 0.f, a1z = 0.f;
    float o2x = p0x, o2y = p0y, o2z = p0z;
    float o3x = p0x, o3y = p0y, o3z = p0z;
    int count = 1;

    // ---- iterative greedy scan (all decisions wave-uniform) ----
    #pragma unroll 1
    for (int it = 1; it < NQ; ++it) {
        u32 gm;
        const int n = argmax_dpp(gm);
        if (gm == 0u) break;                        // keys exhausted
        consume(n);
        const float px = pb[n * 3 + 0];             // broadcast 1-line load
        const float py = pb[n * 3 + 1];
        const float pz = pb[n * 3 + 2];
        const bool add = passv(p1x, p1y, p1z, px, py, pz) &&
                         passv(a1x, a1y, a1z, px, py, pz);
        if (add) {
            if (count == 1) {
                o2x = px; o2y = py; o2z = pz;
                a1x = px; a1y = py; a1z = pz;
                count = 2;
            } else {
                o3x = px; o3y = py; o3z = pz;
                break;                              // 3 accepted
            }
        }
    }

    if (lane == 0) {
        float* ob = out + (size_t)b * 9;
        ob[0] = p1x; ob[1] = p1y; ob[2] = p1z;
        ob[3] = o2x; ob[4] = o2y; ob[5] = o2z;
        ob[6] = o3x; ob[7] = o3y; ob[8] = o3z;
    }
}

extern "C" void kernel_launch(void* const* d_in, const int* in_sizes, int n_in,
                              void* d_out, int out_size, void* d_ws, size_t ws_size,
                              hipStream_t stream) {
    const float* pred_logits = (const float*)d_in[0]; // [B, NQ, 1]
    const float* pred_pos    = (const float*)d_in[1]; // [B, NQ, 3]
    float* out = (float*)d_out;                       // [B, NUM, 3]

    const int grid = B_TOTAL / 4;                     // 4 waves/block
    greedy_nms_kernel<<<grid, 256, 0, stream>>>(pred_logits, pred_pos, out);
}